// Round 8
// baseline (222.691 us; speedup 1.0000x reference)
//
#include <hip/hip_runtime.h>

constexpr int Bn  = 4;
constexpr int Sn  = 1024;
constexpr int Dn  = 1024;
constexpr int Hn  = 16;
constexpr int HDn = 64;

using short8   = __attribute__((ext_vector_type(8))) short;
using float4v  = __attribute__((ext_vector_type(4))) float;
using float16v = __attribute__((ext_vector_type(16))) float;

__device__ __forceinline__ ushort f2bf(float f) {
    union { float f; unsigned u; } v; v.f = f;
    unsigned r = v.u + 0x7fff + ((v.u >> 16) & 1);   // RNE
    return (ushort)(r >> 16);
}

__device__ __forceinline__ void gload16(const void* g, void* l) {
    __builtin_amdgcn_global_load_lds(
        (const __attribute__((address_space(1))) void*)g,
        (__attribute__((address_space(3))) void*)l, 16, 0, 0);
}

// ---------------------------------------------------------------------------
// prep (fused): [0,2048) convert_x | [2048,2816) transpose_w |
//               [2816,2944) build_mask + adj->out copy
// Mask: per-pair halfword masks (0xFFFF=keep) in PV-pack fragment order.
//   rid = ((b*32+qsub)*16+kt)*64+lane; 16 words at Mb+rid*16, index mt*8+pr.
//   pair pr covers keys kt*64 + mt*32 + (2pr&3) + 8*(2pr>>2) + 4*hi + {0,1};
//   q = qsub*32 + (lane&31).
// ---------------------------------------------------------------------------
__global__ __launch_bounds__(256) void prep(
    const float* __restrict__ x,
    const float* __restrict__ Wq, const float* __restrict__ Wk,
    const float* __restrict__ Wv, const float* __restrict__ adj,
    ushort* __restrict__ xb, ushort* __restrict__ Wt, uint* __restrict__ Mb,
    float* __restrict__ out)
{
    const int bx  = blockIdx.x;
    const int tid = threadIdx.x;
    __shared__ __align__(16) ushort T[64 * 72];
    __shared__ char msk[32][64];

    if (bx < 2048) {
        // ---- convert_x ----
        const size_t i = ((size_t)bx * 256 + tid) * 8;
        float4 a = *(const float4*)&x[i];
        float4 b = *(const float4*)&x[i + 4];
        ushort o[8] = {f2bf(a.x), f2bf(a.y), f2bf(a.z), f2bf(a.w),
                       f2bf(b.x), f2bf(b.y), f2bf(b.z), f2bf(b.w)};
        *(uint4*)&xb[i] = *(const uint4*)o;
    } else if (bx < 2816) {
        // ---- transpose_w: W (KxN fp32) -> Wt (NxK bf16) ----
        const int idx = bx - 2048;
        const int which = idx >> 8, rem = idx & 255;
        const float* __restrict__ W = (which == 0) ? Wq : (which == 1) ? Wk : Wv;
        ushort* __restrict__ O = Wt + (size_t)which * Dn * Dn;
        const int k0 = (rem & 15) * 64, n0 = (rem >> 4) * 64;

        const int kl = tid >> 4, nl = (tid & 15) * 4;
#pragma unroll
        for (int p = 0; p < 4; ++p) {
            float4 w4 = *(const float4*)&W[(size_t)(k0 + p * 16 + kl) * Dn + n0 + nl];
            T[(nl + 0) * 72 + p * 16 + kl] = f2bf(w4.x);
            T[(nl + 1) * 72 + p * 16 + kl] = f2bf(w4.y);
            T[(nl + 2) * 72 + p * 16 + kl] = f2bf(w4.z);
            T[(nl + 3) * 72 + p * 16 + kl] = f2bf(w4.w);
        }
        __syncthreads();
        const int nr = tid >> 2, kc = (tid & 3) * 16;
        uint4 u0 = *(const uint4*)&T[nr * 72 + kc];
        uint4 u1 = *(const uint4*)&T[nr * 72 + kc + 8];
        *(uint4*)&O[(size_t)(n0 + nr) * Dn + k0 + kc]     = u0;
        *(uint4*)&O[(size_t)(n0 + nr) * Dn + k0 + kc + 8] = u1;
    } else {
        // ---- build_mask + adj passthrough copy ----
        const int idx = bx - 2816;           // 0..127
        const int b = idx >> 5, qsub = idx & 31;
        const float* abase = adj + ((size_t)b * Sn + qsub * 32) * Sn;
        float* ocopy = out + (size_t)Bn * Sn * Dn + ((size_t)b * Sn + qsub * 32) * Sn;

        const int row = tid >> 3, cc = (tid & 7) * 8;      // 32 rows x 64 cols / 8
        const int lane = tid & 63, part = tid >> 6;
        const int col = lane & 31, hi = lane >> 5;

        for (int kt = 0; kt < 16; ++kt) {
            const size_t off = (size_t)row * Sn + kt * 64 + cc;
            float4 a0 = *(const float4*)&abase[off];
            float4 a1 = *(const float4*)&abase[off + 4];
            *(float4*)&ocopy[off]     = a0;
            *(float4*)&ocopy[off + 4] = a1;
            char* mrow = &msk[row][cc];
            mrow[0] = a0.x >= 0.5f; mrow[1] = a0.y >= 0.5f;
            mrow[2] = a0.z >= 0.5f; mrow[3] = a0.w >= 0.5f;
            mrow[4] = a1.x >= 0.5f; mrow[5] = a1.y >= 0.5f;
            mrow[6] = a1.z >= 0.5f; mrow[7] = a1.w >= 0.5f;
            __syncthreads();

            uint w4[4];
#pragma unroll
            for (int i = 0; i < 4; ++i) {
                const int prg = part * 4 + i;            // mt*8+pr
                const int mt = prg >> 3, pr = prg & 7;
                const int r0 = 2 * pr;
                const int kl = mt * 32 + (r0 & 3) + 8 * (r0 >> 2) + 4 * hi;
                w4[i] = (msk[col][kl]     ? 0x0000FFFFu : 0u) |
                        (msk[col][kl + 1] ? 0xFFFF0000u : 0u);
            }
            const size_t rid = ((size_t)(b * 32 + qsub) * 16 + kt) * 64 + lane;
            *(uint4*)&Mb[rid * 16 + part * 4] = make_uint4(w4[0], w4[1], w4[2], w4[3]);
            __syncthreads();
        }
    }
}

// ---------------------------------------------------------------------------
// bf16 MFMA GEMM: Q pre-scaled by 0.125*log2(e); Q/K -> [B,H,S,HD] (direct),
// V -> [B,H,HD,S] via LDS-transposed coalesced epilogue.
// ---------------------------------------------------------------------------
__global__ __launch_bounds__(256) void qkv_gemm(
    const ushort* __restrict__ xb, const ushort* __restrict__ Wt,
    const float* __restrict__ bq, const float* __restrict__ bk,
    const float* __restrict__ bv,
    ushort* __restrict__ Qb, ushort* __restrict__ Kb, ushort* __restrict__ Vb)
{
    const int which = blockIdx.z;
    const ushort* __restrict__ Bw   = Wt + (size_t)which * Dn * Dn;
    const float* __restrict__  bias = (which == 0) ? bq : (which == 1) ? bk : bv;
    ushort* __restrict__       Out  = (which == 0) ? Qb : (which == 1) ? Kb : Vb;
    const float scale = (which == 0) ? 0.18033688011112042f : 1.0f;  // 0.125*log2(e)

    const int n0   = blockIdx.x * 128;
    const int m0   = blockIdx.y * 128;
    const int tid  = threadIdx.x;
    const int wave = tid >> 6;
    const int lane = tid & 63;
    const int wm   = wave >> 1;
    const int wn   = wave & 1;

    // pool: As (128*32) | Bs (128*32) during K-loop; C2 (128*136) in V epilogue
    __shared__ __align__(16) ushort pool[128 * 136];
    ushort* As = pool;
    ushort* Bs = pool + 128 * 32;

    const int L0 = wave * 64 + lane;
    const int r0s = L0 >> 2, c0s = (L0 & 3) * 8;
    const int L1 = L0 + 256;
    const int r1s = L1 >> 2, c1s = (L1 & 3) * 8;

    const ushort* pA0 = &xb[(size_t)(m0 + r0s) * Dn + c0s];
    const ushort* pA1 = &xb[(size_t)(m0 + r1s) * Dn + c1s];
    const ushort* pB0 = &Bw[(size_t)(n0 + r0s) * Dn + c0s];
    const ushort* pB1 = &Bw[(size_t)(n0 + r1s) * Dn + c1s];

    char* ldsA0 = (char*)As + wave * 1024;
    char* ldsA1 = (char*)As + wave * 1024 + 4096;
    char* ldsB0 = (char*)Bs + wave * 1024;
    char* ldsB1 = (char*)Bs + wave * 1024 + 4096;

    const int mlane = lane & 15;
    const int kg    = (lane >> 4) * 8;

    float4v acc[4][4];
    const float4v z4 = {0.f, 0.f, 0.f, 0.f};
#pragma unroll
    for (int i = 0; i < 4; ++i)
#pragma unroll
        for (int j = 0; j < 4; ++j) acc[i][j] = z4;

    for (int k0 = 0; k0 < Dn; k0 += 32) {
        __syncthreads();
        gload16(pA0, ldsA0);
        gload16(pA1, ldsA1);
        gload16(pB0, ldsB0);
        gload16(pB1, ldsB1);
        pA0 += 32; pA1 += 32; pB0 += 32; pB1 += 32;
        __syncthreads();

        short8 af[4], bf[4];
#pragma unroll
        for (int i = 0; i < 4; ++i)
            af[i] = *(const short8*)&As[(wm * 64 + i * 16 + mlane) * 32 + kg];
#pragma unroll
        for (int j = 0; j < 4; ++j)
            bf[j] = *(const short8*)&Bs[(wn * 64 + j * 16 + mlane) * 32 + kg];
#pragma unroll
        for (int i = 0; i < 4; ++i)
#pragma unroll
            for (int j = 0; j < 4; ++j)
                acc[i][j] = __builtin_amdgcn_mfma_f32_16x16x32_bf16(af[i], bf[j], acc[i][j], 0, 0, 0);
    }

    const int rb  = (lane >> 4) * 4;
    const int col = lane & 15;

    if (which == 2) {
        // ---- V epilogue: pack to C2[n][m] (stride 136), coalesced store ----
        __syncthreads();   // all waves done reading As/Bs
        ushort* C2 = pool;
#pragma unroll
        for (int j = 0; j < 4; ++j) {
            const int n = wn * 64 + j * 16 + col;
            const float bias_n = bias[n0 + n];
#pragma unroll
            for (int i = 0; i < 4; ++i) {
                ushort h4[4];
#pragma unroll
                for (int r = 0; r < 4; ++r) h4[r] = f2bf(acc[i][j][r] + bias_n);
                *(uint2*)&C2[n * 136 + wm * 64 + i * 16 + rb] = *(const uint2*)h4;
            }
        }
        __syncthreads();
        const int n  = tid >> 1, mh = (tid & 1) * 64;
        const int gn = n0 + n, hh = gn >> 6, hd = gn & 63;
        const int bb = m0 >> 10, s0 = (m0 & 1023) + mh;
        ushort* dst = &Out[(((size_t)(bb * Hn + hh)) * HDn + hd) * Sn + s0];
#pragma unroll
        for (int c = 0; c < 8; ++c)
            *(uint4*)&dst[c * 8] = *(const uint4*)&C2[n * 136 + mh + c * 8];
    } else {
        // ---- Q/K epilogue: direct (rows of 32B segments, acceptable) ----
#pragma unroll
        for (int j = 0; j < 4; ++j) {
            const int n  = n0 + wn * 64 + j * 16 + col;
            const float bias_n = bias[n];
            const int h  = n >> 6;
            const int hd = n & 63;
#pragma unroll
            for (int i = 0; i < 4; ++i) {
#pragma unroll
                for (int r = 0; r < 4; ++r) {
                    const int m = m0 + wm * 64 + i * 16 + rb + r;
                    const int b = m >> 10;
                    const int s = m & 1023;
                    Out[(((size_t)(b * Hn + h)) * Sn + s) * HDn + hd] =
                        f2bf((acc[i][j][r] + bias_n) * scale);
                }
            }
        }
    }
}

// ---------------------------------------------------------------------------
// MFMA flash attention, 32x32x16, P in registers (shfl C->B), pair-masks,
// exp2 softmax, deferred additive row sum.
// Block = 64 q of one (b,h); 4 waves split (q-tile jt, kt-half kh);
// partials combine additively via LDS (no-max softmax => exact).
// grid (16,16,4) = 1024 blocks = 4 blocks/CU. LDS 36 KB, stride 72, dbuf.
// ---------------------------------------------------------------------------
__global__ __launch_bounds__(256, 4) void attn_mfma(
    const ushort* __restrict__ Q, const ushort* __restrict__ K,
    const ushort* __restrict__ Vt, const uint* __restrict__ Mw,
    float* __restrict__ out)
{
    const int qt = blockIdx.x, h = blockIdx.y, b = blockIdx.z;
    const int tid  = threadIdx.x;
    const int w    = tid >> 6, lane = tid & 63;
    const int col  = lane & 31, hi = lane >> 5;
    const int jt   = w & 1, kh = w >> 1;
    const int qsub = qt * 2 + jt;                 // 0..31 (32-q tile index)

    const size_t hb = ((size_t)(b * Hn + h)) * Sn * HDn;
    const ushort* Kg = K + hb;          // [key][dim]
    const ushort* Vg = Vt + hb;         // [dim][key]

    __shared__ __align__(16) ushort Ks[2][64 * 72];
    __shared__ __align__(16) ushort Vs[2][64 * 72];

    // Q B-frags (registers, all kt): B[k=dim][n=q], n=col, k=kp*16+hi*8+i
    short8 qf[4];
#pragma unroll
    for (int kp = 0; kp < 4; ++kp)
        qf[kp] = *(const short8*)&Q[hb +
            (size_t)(qsub * 32 + col) * HDn + kp * 16 + hi * 8];

    float16v o_[2];
#pragma unroll
    for (int dt = 0; dt < 2; ++dt)
#pragma unroll
        for (int r = 0; r < 16; ++r) o_[dt][r] = 0.f;
    float ls = 0.f;

    const int c0 = tid, c1 = tid + 256;
    const int la0 = (c0 >> 3) * 72 + (c0 & 7) * 8;
    const int la1 = (c1 >> 3) * 72 + (c1 & 7) * 8;

    uint4 k0 = *(const uint4*)&Kg[(size_t)(c0 >> 3) * HDn + (c0 & 7) * 8];
    uint4 k1 = *(const uint4*)&Kg[(size_t)(c1 >> 3) * HDn + (c1 & 7) * 8];
    uint4 v0 = *(const uint4*)&Vg[(size_t)(c0 >> 3) * Sn + (c0 & 7) * 8];
    uint4 v1 = *(const uint4*)&Vg[(size_t)(c1 >> 3) * Sn + (c1 & 7) * 8];
    *(uint4*)&Ks[0][la0] = k0;  *(uint4*)&Ks[0][la1] = k1;
    *(uint4*)&Vs[0][la0] = v0;  *(uint4*)&Vs[0][la1] = v1;
    __syncthreads();

    const uint* mb0 = Mw + (((size_t)(b * 32 + qsub) * 16) * 64 + lane) * 16;

    for (int kt = 0; kt < 16; ++kt) {
        const int cur = kt & 1;
        if (kt < 15) {
            k0 = *(const uint4*)&Kg[(size_t)((kt + 1) * 64 + (c0 >> 3)) * HDn + (c0 & 7) * 8];
            k1 = *(const uint4*)&Kg[(size_t)((kt + 1) * 64 + (c1 >> 3)) * HDn + (c1 & 7) * 8];
            v0 = *(const uint4*)&Vg[(size_t)(c0 >> 3) * Sn + (kt + 1) * 64 + (c0 & 7) * 8];
            v1 = *(const uint4*)&Vg[(size_t)(c1 >> 3) * Sn + (kt + 1) * 64 + (c1 & 7) * 8];
        }

        if ((kt >> 3) == kh) {
            const uint* mp = mb0 + (size_t)kt * 1024;
            uint4 mk4[4];
            mk4[0] = *(const uint4*)(mp);
            mk4[1] = *(const uint4*)(mp + 4);
            mk4[2] = *(const uint4*)(mp + 8);
            mk4[3] = *(const uint4*)(mp + 12);
            const uint* mka = (const uint*)mk4;

#pragma unroll
            for (int mt = 0; mt < 2; ++mt) {
                float16v s_;
#pragma unroll
                for (int r = 0; r < 16; ++r) s_[r] = 0.f;
#pragma unroll
                for (int kp = 0; kp < 4; ++kp) {
                    short8 ak = *(const short8*)&Ks[cur][(mt * 32 + col) * 72 + kp * 16 + hi * 8];
                    s_ = __builtin_amdgcn_mfma_f32_32x32x16_bf16(ak, qf[kp], s_, 0, 0, 0);
                }

                unsigned up[8];
#pragma unroll
                for (int pr = 0; pr < 8; ++pr) {
                    const unsigned e0 = __float_as_uint(exp2f(s_[2 * pr]))     + 0x8000u;
                    const unsigned e1 = __float_as_uint(exp2f(s_[2 * pr + 1])) + 0x8000u;
                    const unsigned u  = __builtin_amdgcn_perm(e1, e0, 0x07060302u) & mka[mt * 8 + pr];
                    up[pr] = u;
                    ls += __uint_as_float(u << 16) + __uint_as_float(u & 0xffff0000u);
                }

#pragma unroll
                for (int kkh = 0; kkh < 2; ++kkh) {
                    const unsigned a0 = up[kkh * 4 + 0], a1 = up[kkh * 4 + 1];
                    const unsigned a2 = up[kkh * 4 + 2], a3 = up[kkh * 4 + 3];
                    const unsigned t0 = (unsigned)__shfl_xor((int)(hi ? a0 : a2), 32, 64);
                    const unsigned t1 = (unsigned)__shfl_xor((int)(hi ? a1 : a3), 32, 64);
                    union { short8 s; unsigned u[4]; } f;
                    f.u[0] = hi ? t0 : a0;
                    f.u[1] = hi ? t1 : a1;
                    f.u[2] = hi ? a2 : t0;
                    f.u[3] = hi ? a3 : t1;
                    const int kp = mt * 2 + kkh;
#pragma unroll
                    for (int dt = 0; dt < 2; ++dt) {
                        short8 av = *(const short8*)&Vs[cur][(dt * 32 + col) * 72 + kp * 16 + hi * 8];
                        o_[dt] = __builtin_amdgcn_mfma_f32_32x32x16_bf16(av, f.s, o_[dt], 0, 0, 0);
                    }
                }
            }
        }

        if (kt < 15) {
            const int nxt = cur ^ 1;
            *(uint4*)&Ks[nxt][la0] = k0;  *(uint4*)&Ks[nxt][la1] = k1;
            *(uint4*)&Vs[nxt][la0] = v0;  *(uint4*)&Vs[nxt][la1] = v1;
        }
        __syncthreads();
    }

    // ---- combine kt-half partials (additive: no-max softmax) via Ks scratch ----
    float* red = (float*)Ks;    // 2 jt x 64 lanes x 36 floats = 18432 B = sizeof(Ks)
    if (kh == 1) {
        float* p = red + (size_t)(jt * 64 + lane) * 36;
#pragma unroll
        for (int dt = 0; dt < 2; ++dt)
#pragma unroll
            for (int c = 0; c < 4; ++c)
                *(float4*)&p[dt * 16 + c * 4] = make_float4(
                    o_[dt][c * 4 + 0], o_[dt][c * 4 + 1],
                    o_[dt][c * 4 + 2], o_[dt][c * 4 + 3]);
        p[32] = ls;
    }
    __syncthreads();
    if (kh == 0) {
        const float* p = red + (size_t)(jt * 64 + lane) * 36;
#pragma unroll
        for (int dt = 0; dt < 2; ++dt)
#pragma unroll
            for (int r = 0; r < 16; ++r) o_[dt][r] += p[dt * 16 + r];
        ls += p[32];

        float l = ls + (float)__shfl_xor((float)ls, 32, 64);
        const float inv = 1.0f / l;
        const int q = qsub * 32 + col;
        float* op = &out[((size_t)b * Sn + q) * Dn + h * 64];
#pragma unroll
        for (int dt = 0; dt < 2; ++dt)
#pragma unroll
            for (int rg = 0; rg < 4; ++rg) {
                const int d = dt * 32 + rg * 8 + hi * 4;
                float4 o4;
                o4.x = fmaxf(o_[dt][rg * 4 + 0] * inv, 0.0f);
                o4.y = fmaxf(o_[dt][rg * 4 + 1] * inv, 0.0f);
                o4.z = fmaxf(o_[dt][rg * 4 + 2] * inv, 0.0f);
                o4.w = fmaxf(o_[dt][rg * 4 + 3] * inv, 0.0f);
                *(float4*)&op[d] = o4;
            }
    }
}

extern "C" void kernel_launch(void* const* d_in, const int* in_sizes, int n_in,
                              void* d_out, int out_size, void* d_ws, size_t ws_size,
                              hipStream_t stream)
{
    const float* x   = (const float*)d_in[0];
    const float* adj = (const float*)d_in[1];
    const float* Wq  = (const float*)d_in[2];
    const float* bq  = (const float*)d_in[3];
    const float* Wk  = (const float*)d_in[4];
    const float* bk  = (const float*)d_in[5];
    const float* Wv  = (const float*)d_in[6];
    const float* bv  = (const float*)d_in[7];
    float* out = (float*)d_out;

    // ws (ushort): xb[4.19M] | Wt[3.15M] | Qb | Kb | Vb [4.19M ea] then Mb (uint, 8.4 MB)
    ushort* xb = (ushort*)d_ws;
    ushort* Wt = xb + (size_t)Bn * Sn * Dn;
    ushort* Qb = Wt + (size_t)3 * Dn * Dn;
    ushort* Kb = Qb + (size_t)Bn * Hn * Sn * HDn;
    ushort* Vb = Kb + (size_t)Bn * Hn * Sn * HDn;
    uint*   Mb = (uint*)(Vb + (size_t)Bn * Hn * Sn * HDn);

    prep<<<dim3(2944), 256, 0, stream>>>(x, Wq, Wk, Wv, adj, xb, Wt, Mb, out);

    qkv_gemm<<<dim3(Dn / 128, (Bn * Sn) / 128, 3), 256, 0, stream>>>(
        xb, Wt, bq, bk, bv, Qb, Kb, Vb);

    attn_mfma<<<dim3(16, Hn, Bn), 256, 0, stream>>>(Qb, Kb, Vb, Mb, out);
}